// Round 2
// baseline (3108.101 us; speedup 1.0000x reference)
//
#include <hip/hip_runtime.h>
#include <hip/hip_bf16.h>
#include <math.h>

// MoE: T=65536 tokens, D=512, H=1024, E=8, TOP_K=2.
// Gate fp32 (selection fidelity), experts bf16 MFMA with 8-phase
// prefetch-issue-then-compute schedule + global_load_lds(16B) staging.

typedef __attribute__((ext_vector_type(8))) short bf16x8;
typedef __attribute__((ext_vector_type(4))) float f32x4;
typedef unsigned short ushort_t;

__device__ __forceinline__ unsigned short f2bf(float f){
  unsigned u = __builtin_bit_cast(unsigned, f);
  u += 0x7FFFu + ((u >> 16) & 1u);          // RNE
  return (unsigned short)(u >> 16);
}

__device__ __forceinline__ bf16x8 cvt8(float4 f0, float4 f1){
  bf16x8 r;
  r[0]=(short)f2bf(f0.x); r[1]=(short)f2bf(f0.y); r[2]=(short)f2bf(f0.z); r[3]=(short)f2bf(f0.w);
  r[4]=(short)f2bf(f1.x); r[5]=(short)f2bf(f1.y); r[6]=(short)f2bf(f1.z); r[7]=(short)f2bf(f1.w);
  return r;
}

__device__ __forceinline__ void gload16(const void* g, void* l){
  __builtin_amdgcn_global_load_lds((const __attribute__((address_space(1))) unsigned int*)g,
                                   (__attribute__((address_space(3))) unsigned int*)l, 16, 0, 0);
}

// ---------------------------------------------------------------------------
// Transpose + fp32->bf16 convert:  in [E][R][C] f32  ->  out [E][C][R] bf16
// ---------------------------------------------------------------------------
__global__ __launch_bounds__(256, 4)
void transpose_cvt_kernel(const float* __restrict__ in, unsigned short* __restrict__ out,
                          int R, int C){
  const int tilesR = R >> 6, tilesC = C >> 6;
  const int b = blockIdx.x;
  const int e = b / (tilesR * tilesC);
  const int rem = b % (tilesR * tilesC);
  const int rb = (rem / tilesC) << 6;
  const int cb = (rem % tilesC) << 6;
  const float* src = in + (size_t)e * R * C;
  unsigned short* dst = out + (size_t)e * R * C;
  __shared__ float t[64][65];
  const int r0 = threadIdx.x >> 4;
  const int c4 = (threadIdx.x & 15) << 2;
  #pragma unroll
  for (int p = 0; p < 4; ++p){
    int r = r0 + (p << 4);
    const float4 v = *(const float4*)(src + (size_t)(rb + r) * C + cb + c4);
    t[r][c4+0] = v.x; t[r][c4+1] = v.y; t[r][c4+2] = v.z; t[r][c4+3] = v.w;
  }
  __syncthreads();
  #pragma unroll
  for (int p = 0; p < 4; ++p){
    int cr = r0 + (p << 4);
    ushort4 o;
    o.x = f2bf(t[c4+0][cr]); o.y = f2bf(t[c4+1][cr]);
    o.z = f2bf(t[c4+2][cr]); o.w = f2bf(t[c4+3][cr]);
    *(ushort4*)(dst + (size_t)(cb + cr) * R + rb + c4) = o;
  }
}

// ---------------------------------------------------------------------------
// Gate: fp32 GEMM1(512->256)+relu, GEMM2(256->8), softmax, top2, re-softmax.
// Block = 128 tokens, 512 threads; thread tile 8 tokens x 8 cols.
// tg = tid>>5 (16 token-groups), cg = tid&31 (32 col-groups of 8).
// ---------------------------------------------------------------------------
__global__ __launch_bounds__(512, 2)
void gate_kernel(const float* __restrict__ x, const float* __restrict__ gw1,
                 const float* __restrict__ gb1, const float* __restrict__ gw2,
                 const float* __restrict__ gb2,
                 int* __restrict__ counts, int* __restrict__ pair_tok,
                 float* __restrict__ pair_w){
  __shared__ float xs[32 * 132];        // [k][tok], stride 132 (16B-aligned rows)
  __shared__ float g1s[32 * 256];       // [k][col]
  __shared__ float g2s[256 * 9];
  __shared__ float b1s[256];
  const int tid = threadIdx.x;
  const int t0 = blockIdx.x << 7;
  const int tg = tid >> 5, cg = tid & 31;

  for (int p = tid; p < 2048; p += 512) g2s[(p >> 3) * 9 + (p & 7)] = gw2[p];
  if (tid < 256) b1s[tid] = gb1[tid];

  float acc[8][8];
  #pragma unroll
  for (int t = 0; t < 8; ++t)
    #pragma unroll
    for (int j = 0; j < 8; ++j) acc[t][j] = 0.f;

  for (int kb = 0; kb < 512; kb += 32){
    __syncthreads();                    // previous iter's reads done
    #pragma unroll
    for (int p = 0; p < 2; ++p){        // stage x: 128 tok x 32 k, transposed
      int f = tid + (p << 9);
      int tok = f >> 3, kq = (f & 7) << 2;
      const float4 v = *(const float4*)(x + (size_t)(t0 + tok) * 512 + kb + kq);
      xs[(kq+0)*132 + tok] = v.x; xs[(kq+1)*132 + tok] = v.y;
      xs[(kq+2)*132 + tok] = v.z; xs[(kq+3)*132 + tok] = v.w;
    }
    #pragma unroll
    for (int p = 0; p < 4; ++p){        // stage gw1: 32 k x 256 col
      int f = tid + (p << 9);
      int r = f >> 6, c = (f & 63) << 2;
      *(float4*)&g1s[r * 256 + c] = *(const float4*)(gw1 + (size_t)(kb + r) * 256 + c);
    }
    __syncthreads();
    #pragma unroll 4
    for (int k = 0; k < 32; ++k){
      float xv[8], wv[8];
      *(float4*)&xv[0] = *(const float4*)&xs[k*132 + (tg << 3)];
      *(float4*)&xv[4] = *(const float4*)&xs[k*132 + (tg << 3) + 4];
      *(float4*)&wv[0] = *(const float4*)&g1s[k*256 + (cg << 3)];
      *(float4*)&wv[4] = *(const float4*)&g1s[k*256 + (cg << 3) + 4];
      #pragma unroll
      for (int t = 0; t < 8; ++t)
        #pragma unroll
        for (int j = 0; j < 8; ++j)
          acc[t][j] = fmaf(xv[t], wv[j], acc[t][j]);
    }
  }

  // bias + relu + GEMM2 partials over this thread's 8 cols
  float pl[8][8];
  #pragma unroll
  for (int t = 0; t < 8; ++t)
    #pragma unroll
    for (int e = 0; e < 8; ++e) pl[t][e] = 0.f;
  #pragma unroll
  for (int j = 0; j < 8; ++j){
    int col = (cg << 3) + j;
    float bias = b1s[col];
    #pragma unroll
    for (int t = 0; t < 8; ++t){
      float h = fmaxf(acc[t][j] + bias, 0.f);
      #pragma unroll
      for (int e = 0; e < 8; ++e)
        pl[t][e] = fmaf(h, g2s[col * 9 + e], pl[t][e]);
    }
  }
  // reduce across the 32 col-groups (lanes cg 0..31 within each half-wave)
  #pragma unroll
  for (int m = 1; m <= 16; m <<= 1)
    #pragma unroll
    for (int t = 0; t < 8; ++t)
      #pragma unroll
      for (int e = 0; e < 8; ++e)
        pl[t][e] += __shfl_xor(pl[t][e], m, 64);

  if (cg == 0){
    #pragma unroll
    for (int t = 0; t < 8; ++t){
      int token = t0 + (tg << 3) + t;
      float lg[8];
      #pragma unroll
      for (int e = 0; e < 8; ++e) lg[e] = pl[t][e] + gb2[e];
      float m = lg[0];
      #pragma unroll
      for (int e = 1; e < 8; ++e) m = fmaxf(m, lg[e]);
      float p[8]; float s = 0.f;
      #pragma unroll
      for (int e = 0; e < 8; ++e){ p[e] = expf(lg[e] - m); s += p[e]; }
      float inv = 1.f / s;
      float m1 = -1.f, m2 = -1.f; int i1 = 0, i2 = 0;
      #pragma unroll
      for (int e = 0; e < 8; ++e){
        float pe = p[e] * inv;
        if (pe > m1){ m2 = m1; i2 = i1; m1 = pe; i1 = e; }
        else if (pe > m2){ m2 = pe; i2 = e; }
      }
      float e21 = expf(m2 - m1);
      float w1 = 1.f / (1.f + e21);
      float w2 = 1.f - w1;
      int pos1 = atomicAdd(&counts[i1], 1);
      pair_tok[(i1 << 16) + pos1] = token; pair_w[(i1 << 16) + pos1] = w1;
      int pos2 = atomicAdd(&counts[i2], 1);
      pair_tok[(i2 << 16) + pos2] = token; pair_w[(i2 << 16) + pos2] = w2;
    }
  }
}

// ---------------------------------------------------------------------------
// Expert MLP. Block = (expert e = blockIdx&7 -> XCD-pinned) x 64 tokens.
// 256 thr, 4 waves x 16 token-rows. 8 phases per hc-chunk, 1 barrier each:
//   issue next stage (global_load_lds, pre-swizzled source) -> compute 16 MFMA.
// ---------------------------------------------------------------------------
#define G1_PHASE(S, BUF) do{ \
  _Pragma("unroll") \
  for (int ct = 0; ct < 4; ++ct){ \
    const int col = (ct << 4) + lrow; \
    const int swc = (col & 7) << 4; \
    _Pragma("unroll") \
    for (int k2 = 0; k2 < 4; ++k2){ \
      const int byt = (col << 8) + (((k2 << 6) + (kgrp << 4)) ^ swc); \
      bf16x8 bfr = *(const bf16x8*)((const char*)(BUF) + byt); \
      hacc[ct] = __builtin_amdgcn_mfma_f32_16x16x32_bf16(a[(S)*4 + k2], bfr, hacc[ct], 0, 0, 0); \
    } \
  } \
}while(0)

#define G2_PHASE(NB, BUF) do{ \
  _Pragma("unroll") \
  for (int nt = 0; nt < 8; ++nt){ \
    const int col = (nt << 4) + lrow; \
    const int swc = (col & 7) << 4; \
    _Pragma("unroll") \
    for (int k2 = 0; k2 < 2; ++k2){ \
      const int byt = (col << 7) + (((k2 << 6) + (kgrp << 4)) ^ swc); \
      bf16x8 bfr = *(const bf16x8*)((const char*)(BUF) + byt); \
      acc[(NB)*8 + nt] = __builtin_amdgcn_mfma_f32_16x16x32_bf16(a2[k2], bfr, acc[(NB)*8 + nt], 0, 0, 0); \
    } \
  } \
}while(0)

__global__ __launch_bounds__(256, 2)
void expert_kernel(const float* __restrict__ x,
                   const unsigned short* __restrict__ we1T,  // [E][1024][512] bf16
                   const unsigned short* __restrict__ we2T,  // [E][512][1024] bf16
                   const float* __restrict__ be1, const float* __restrict__ be2,
                   const int* __restrict__ counts, const int* __restrict__ pair_tok,
                   const float* __restrict__ pair_w,
                   float* __restrict__ out){
  const int e = blockIdx.x & 7;          // XCD-pinned: expert e -> XCD e
  const int blk = blockIdx.x >> 3;
  const int cnt = counts[e];
  const int base = blk << 6;
  if (base >= cnt) return;
  const int tid = threadIdx.x;
  const int wv = tid >> 6;
  const int lane = tid & 63;
  const int lrow = lane & 15;
  const int kgrp = lane >> 4;

  __shared__ unsigned short w1s0[64 * 128];   // [hcol][k0..127] 16KB
  __shared__ unsigned short w1s1[64 * 128];
  __shared__ unsigned short w2s0[128 * 64];   // [dcol][k0..63]  16KB
  __shared__ unsigned short w2s1[128 * 64];
  __shared__ unsigned short hs[64 * 64];      // [row][k]        8KB

  // A fragments: x rows (bf16), full K=512: a[kc] = k in [kc*32, +32)
  bf16x8 a[16];
  {
    int r = base + (wv << 4) + lrow;
    int tok = (r < cnt) ? pair_tok[(e << 16) + r] : 0;
    const float* xr = x + (size_t)tok * 512 + (kgrp << 3);
    #pragma unroll
    for (int kc = 0; kc < 16; ++kc){
      const float4 f0 = *(const float4*)(xr + (kc << 5));
      const float4 f1 = *(const float4*)(xr + (kc << 5) + 4);
      a[kc] = cvt8(f0, f1);
    }
  }
  f32x4 acc[32];
  #pragma unroll
  for (int i = 0; i < 32; ++i) acc[i] = (f32x4)0.f;

  const unsigned short* w1g = we1T + ((size_t)e << 19);
  const unsigned short* w2g = we2T + ((size_t)e << 19);

  // stage helpers (lambdas keep static unroll; all addresses runtime)
  auto stage_w1 = [&](int hcv, int s, unsigned short* buf){
    #pragma unroll
    for (int i = 0; i < 4; ++i){
      int b = (wv << 12) + (i << 10) + (lane << 4);
      int row = b >> 8;
      int inner = b & 255;
      int srcb = ((hcv + row) << 10) + (s << 8) + (inner ^ ((row & 7) << 4));
      gload16((const char*)w1g + srcb, (char*)buf + (wv << 12) + (i << 10));
    }
  };
  auto stage_w2 = [&](int hcv, int nb, unsigned short* buf){
    #pragma unroll
    for (int i = 0; i < 4; ++i){
      int b = (wv << 12) + (i << 10) + (lane << 4);
      int row = b >> 7;
      int inner = b & 127;
      int srcb = (((nb << 7) + row) << 11) + (hcv << 1) + (inner ^ ((row & 7) << 4));
      gload16((const char*)w2g + srcb, (char*)buf + (wv << 12) + (i << 10));
    }
  };

  stage_w1(0, 0, w1s0);
  __syncthreads();

  for (int hc = 0; hc < 1024; hc += 64){
    f32x4 hacc[4];
    #pragma unroll
    for (int i = 0; i < 4; ++i) hacc[i] = (f32x4)0.f;

    stage_w1(hc, 1, w1s1);  G1_PHASE(0, w1s0);  __syncthreads();
    stage_w1(hc, 2, w1s0);  G1_PHASE(1, w1s1);  __syncthreads();
    stage_w1(hc, 3, w1s1);  G1_PHASE(2, w1s0);  __syncthreads();
    stage_w2(hc, 0, w2s0);  G1_PHASE(3, w1s1);
    { // bias + exact gelu + store h (bf16, swizzled)
      char* const hsb = (char*)hs;
      #pragma unroll
      for (int ct = 0; ct < 4; ++ct){
        int colL = (ct << 4) + lrow;
        float bias = be1[(e << 10) + hc + colL];
        #pragma unroll
        for (int rr = 0; rr < 4; ++rr){
          int rowL = (wv << 4) + (kgrp << 2) + rr;
          float v = hacc[ct][rr] + bias;
          float g = 0.5f * v * (1.f + erff(v * 0.70710678118654752f));
          int byt = (rowL << 7) + (colL << 1);
          *(unsigned short*)(hsb + (byt ^ ((rowL & 7) << 4))) = f2bf(g);
        }
      }
    }
    __syncthreads();
    bf16x8 a2[2];
    {
      const char* const hsb = (const char*)hs;
      int rowL = (wv << 4) + lrow;
      int swr = (rowL & 7) << 4;
      #pragma unroll
      for (int k2 = 0; k2 < 2; ++k2){
        int byt = (rowL << 7) + (((k2 << 6) + (kgrp << 4)) ^ swr);
        a2[k2] = *(const bf16x8*)(hsb + byt);
      }
    }
    stage_w2(hc, 1, w2s1);       G2_PHASE(0, w2s0);  __syncthreads();
    stage_w2(hc, 2, w2s0);       G2_PHASE(1, w2s1);  __syncthreads();
    stage_w2(hc, 3, w2s1);       G2_PHASE(2, w2s0);  __syncthreads();
    stage_w1(hc + 64, 0, w1s0);  G2_PHASE(3, w2s1);  __syncthreads();
  }

  // epilogue: weighted atomic accumulate
  #pragma unroll
  for (int rr = 0; rr < 4; ++rr){
    int rowL = (wv << 4) + (kgrp << 2) + rr;
    int rg = base + rowL;
    if (rg < cnt){
      int tok = pair_tok[(e << 16) + rg];
      float wp = pair_w[(e << 16) + rg];
      float* orow = out + (size_t)tok * 512;
      #pragma unroll
      for (int tl = 0; tl < 32; ++tl){
        int col = (tl << 4) + lrow;
        atomicAdd(orow + col, wp * (acc[tl][rr] + be2[(e << 9) + col]));
      }
    }
  }
}

// ---------------------------------------------------------------------------
extern "C" void kernel_launch(void* const* d_in, const int* in_sizes, int n_in,
                              void* d_out, int out_size, void* d_ws, size_t ws_size,
                              hipStream_t stream){
  const float* x   = (const float*)d_in[0];
  const float* gw1 = (const float*)d_in[1];
  const float* gb1 = (const float*)d_in[2];
  const float* gw2 = (const float*)d_in[3];
  const float* gb2 = (const float*)d_in[4];
  const float* we1 = (const float*)d_in[5];
  const float* be1 = (const float*)d_in[6];
  const float* we2 = (const float*)d_in[7];
  const float* be2 = (const float*)d_in[8];
  float* out = (float*)d_out;

  char* ws = (char*)d_ws;
  unsigned short* we1T = (unsigned short*)(ws);                    // 8 MiB
  unsigned short* we2T = (unsigned short*)(ws + 8388608);          // 8 MiB
  int*   counts   = (int*)  (ws + 16777216);                       // 32 B
  int*   pair_tok = (int*)  (ws + 16777472);                       // 2 MiB
  float* pair_w   = (float*)(ws + 16777472 + 2097152);             // 2 MiB

  hipMemsetAsync(d_out, 0, (size_t)out_size * sizeof(float), stream);
  hipMemsetAsync(counts, 0, 32, stream);

  hipLaunchKernelGGL(transpose_cvt_kernel, dim3(1024), dim3(256), 0, stream,
                     we1, we1T, 512, 1024);
  hipLaunchKernelGGL(transpose_cvt_kernel, dim3(1024), dim3(256), 0, stream,
                     we2, we2T, 1024, 512);
  hipLaunchKernelGGL(gate_kernel, dim3(512), dim3(512), 0, stream,
                     x, gw1, gb1, gw2, gb2, counts, pair_tok, pair_w);
  hipLaunchKernelGGL(expert_kernel, dim3(8192), dim3(256), 0, stream,
                     x, we1T, we2T, be1, be2, counts, pair_tok, pair_w, out);
}

// Round 3
// 2214.791 us; speedup vs baseline: 1.4033x; 1.4033x over previous
//
#include <hip/hip_runtime.h>
#include <hip/hip_bf16.h>
#include <math.h>

// MoE: T=65536 tokens, D=512, H=1024, E=8, TOP_K=2.
// Gate fp32 (selection fidelity), experts bf16 MFMA.
// Experts dispatched SEQUENTIALLY (e = blk>>9) across the whole machine:
// weights stay L2-resident on every XCD, atomic out-lines spread over all L2s.
// (R2's XCD pinning caused L2 atomic thrash: WRITE_SIZE 308->940MB. Reverted.)

typedef __attribute__((ext_vector_type(8))) short bf16x8;
typedef __attribute__((ext_vector_type(4))) float f32x4;

__device__ __forceinline__ unsigned short f2bf(float f){
  unsigned u = __builtin_bit_cast(unsigned, f);
  u += 0x7FFFu + ((u >> 16) & 1u);          // RNE
  return (unsigned short)(u >> 16);
}

__device__ __forceinline__ bf16x8 cvt8(float4 f0, float4 f1){
  bf16x8 r;
  r[0]=(short)f2bf(f0.x); r[1]=(short)f2bf(f0.y); r[2]=(short)f2bf(f0.z); r[3]=(short)f2bf(f0.w);
  r[4]=(short)f2bf(f1.x); r[5]=(short)f2bf(f1.y); r[6]=(short)f2bf(f1.z); r[7]=(short)f2bf(f1.w);
  return r;
}

__device__ __forceinline__ void gload16(const void* g, void* l){
  __builtin_amdgcn_global_load_lds((const __attribute__((address_space(1))) unsigned int*)g,
                                   (__attribute__((address_space(3))) unsigned int*)l, 16, 0, 0);
}

// ---------------------------------------------------------------------------
// Transpose + fp32->bf16 convert:  in [E][R][C] f32  ->  out [E][C][R] bf16
// ---------------------------------------------------------------------------
__global__ __launch_bounds__(256, 4)
void transpose_cvt_kernel(const float* __restrict__ in, unsigned short* __restrict__ out,
                          int R, int C){
  const int tilesR = R >> 6, tilesC = C >> 6;
  const int b = blockIdx.x;
  const int e = b / (tilesR * tilesC);
  const int rem = b % (tilesR * tilesC);
  const int rb = (rem / tilesC) << 6;
  const int cb = (rem % tilesC) << 6;
  const float* src = in + (size_t)e * R * C;
  unsigned short* dst = out + (size_t)e * R * C;
  __shared__ float t[64][65];
  const int r0 = threadIdx.x >> 4;
  const int c4 = (threadIdx.x & 15) << 2;
  #pragma unroll
  for (int p = 0; p < 4; ++p){
    int r = r0 + (p << 4);
    const float4 v = *(const float4*)(src + (size_t)(rb + r) * C + cb + c4);
    t[r][c4+0] = v.x; t[r][c4+1] = v.y; t[r][c4+2] = v.z; t[r][c4+3] = v.w;
  }
  __syncthreads();
  #pragma unroll
  for (int p = 0; p < 4; ++p){
    int cr = r0 + (p << 4);
    ushort4 o;
    o.x = f2bf(t[c4+0][cr]); o.y = f2bf(t[c4+1][cr]);
    o.z = f2bf(t[c4+2][cr]); o.w = f2bf(t[c4+3][cr]);
    *(ushort4*)(dst + (size_t)(cb + cr) * R + rb + c4) = o;
  }
}

// ---------------------------------------------------------------------------
// Gate: fp32 GEMM1(512->256)+relu, GEMM2(256->8), softmax, top2, re-softmax.
// Block = 128 tokens, 512 threads; thread (tg=tid>>5, cg=tid&31) owns
// tokens tg*8..+7 and cols {4cg..4cg+3, 128+4cg..+3} (lane-sequential 16B
// g1s reads -> conflict-free; R2's 32B-stride reads were 8-way conflicted).
// ---------------------------------------------------------------------------
__global__ __launch_bounds__(512, 2)
void gate_kernel(const float* __restrict__ x, const float* __restrict__ gw1,
                 const float* __restrict__ gb1, const float* __restrict__ gw2,
                 const float* __restrict__ gb2,
                 int* __restrict__ counts, int* __restrict__ pair_tok,
                 float* __restrict__ pair_w){
  __shared__ float xs[32 * 132];        // [k][tok]
  __shared__ float g1s[32 * 256];       // [k][col]
  __shared__ float g2s[256 * 9];
  __shared__ float b1s[256];
  const int tid = threadIdx.x;
  const int t0 = blockIdx.x << 7;
  const int tg = tid >> 5, cg = tid & 31;

  for (int p = tid; p < 2048; p += 512) g2s[(p >> 3) * 9 + (p & 7)] = gw2[p];
  if (tid < 256) b1s[tid] = gb1[tid];

  float acc[8][8];
  #pragma unroll
  for (int t = 0; t < 8; ++t)
    #pragma unroll
    for (int j = 0; j < 8; ++j) acc[t][j] = 0.f;

  for (int kb = 0; kb < 512; kb += 32){
    __syncthreads();                    // previous iter's reads done
    #pragma unroll
    for (int p = 0; p < 2; ++p){        // stage x: 128 tok x 32 k, transposed
      int f = tid + (p << 9);
      int tok = f >> 3, kq = (f & 7) << 2;
      const float4 v = *(const float4*)(x + (size_t)(t0 + tok) * 512 + kb + kq);
      xs[(kq+0)*132 + tok] = v.x; xs[(kq+1)*132 + tok] = v.y;
      xs[(kq+2)*132 + tok] = v.z; xs[(kq+3)*132 + tok] = v.w;
    }
    #pragma unroll
    for (int p = 0; p < 4; ++p){        // stage gw1: 32 k x 256 col
      int f = tid + (p << 9);
      int r = f >> 6, c4 = (f & 63) << 2;
      *(float4*)&g1s[r * 256 + c4] = *(const float4*)(gw1 + (size_t)(kb + r) * 256 + c4);
    }
    __syncthreads();
    #pragma unroll 4
    for (int k = 0; k < 32; ++k){
      float xv[8], wv[8];
      *(float4*)&xv[0] = *(const float4*)&xs[k*132 + (tg << 3)];
      *(float4*)&xv[4] = *(const float4*)&xs[k*132 + (tg << 3) + 4];
      *(float4*)&wv[0] = *(const float4*)&g1s[k*256 + (cg << 2)];
      *(float4*)&wv[4] = *(const float4*)&g1s[k*256 + 128 + (cg << 2)];
      #pragma unroll
      for (int t = 0; t < 8; ++t)
        #pragma unroll
        for (int j = 0; j < 8; ++j)
          acc[t][j] = fmaf(xv[t], wv[j], acc[t][j]);
    }
  }

  // bias + relu + GEMM2 partials over this thread's 8 cols
  float pl[8][8];
  #pragma unroll
  for (int t = 0; t < 8; ++t)
    #pragma unroll
    for (int e = 0; e < 8; ++e) pl[t][e] = 0.f;
  #pragma unroll
  for (int j = 0; j < 8; ++j){
    int col = (j < 4) ? ((cg << 2) + j) : (128 + (cg << 2) + j - 4);
    float bias = b1s[col];
    #pragma unroll
    for (int t = 0; t < 8; ++t){
      float h = fmaxf(acc[t][j] + bias, 0.f);
      #pragma unroll
      for (int e = 0; e < 8; ++e)
        pl[t][e] = fmaf(h, g2s[col * 9 + e], pl[t][e]);
    }
  }
  // reduce across the 32 col-groups
  #pragma unroll
  for (int m = 1; m <= 16; m <<= 1)
    #pragma unroll
    for (int t = 0; t < 8; ++t)
      #pragma unroll
      for (int e = 0; e < 8; ++e)
        pl[t][e] += __shfl_xor(pl[t][e], m, 64);

  if (cg == 0){
    #pragma unroll
    for (int t = 0; t < 8; ++t){
      int token = t0 + (tg << 3) + t;
      float lg[8];
      #pragma unroll
      for (int e = 0; e < 8; ++e) lg[e] = pl[t][e] + gb2[e];
      float m = lg[0];
      #pragma unroll
      for (int e = 1; e < 8; ++e) m = fmaxf(m, lg[e]);
      float p[8]; float s = 0.f;
      #pragma unroll
      for (int e = 0; e < 8; ++e){ p[e] = expf(lg[e] - m); s += p[e]; }
      float inv = 1.f / s;
      float m1 = -1.f, m2 = -1.f; int i1 = 0, i2 = 0;
      #pragma unroll
      for (int e = 0; e < 8; ++e){
        float pe = p[e] * inv;
        if (pe > m1){ m2 = m1; i2 = i1; m1 = pe; i1 = e; }
        else if (pe > m2){ m2 = pe; i2 = e; }
      }
      float e21 = expf(m2 - m1);
      float w1 = 1.f / (1.f + e21);
      float w2 = 1.f - w1;
      int pos1 = atomicAdd(&counts[i1], 1);
      pair_tok[(i1 << 16) + pos1] = token; pair_w[(i1 << 16) + pos1] = w1;
      int pos2 = atomicAdd(&counts[i2], 1);
      pair_tok[(i2 << 16) + pos2] = token; pair_w[(i2 << 16) + pos2] = w2;
    }
  }
}

// ---------------------------------------------------------------------------
// Expert MLP. Block = 128 tokens of expert e = blk>>9 (sequential experts).
// 512 thr = 8 waves, each owning 16 token-rows. Per hc-chunk (64 hcols):
// 8 phases, each { issue async stage (global_load_lds, pre-swizzled src),
// 16 MFMA (setprio-wrapped), barrier }. Double-buffered w1/w2 tiles.
// ---------------------------------------------------------------------------
#define G1_PHASE(S, BUF) do{ \
  __builtin_amdgcn_s_setprio(1); \
  _Pragma("unroll") \
  for (int ct = 0; ct < 4; ++ct){ \
    const int col = (ct << 4) + lrow; \
    const int swc = (col & 7) << 4; \
    _Pragma("unroll") \
    for (int k2 = 0; k2 < 4; ++k2){ \
      const int byt = (col << 8) + ((((k2) << 6) + (kgrp << 4)) ^ swc); \
      bf16x8 bfr = *(const bf16x8*)((const char*)(BUF) + byt); \
      hacc[ct] = __builtin_amdgcn_mfma_f32_16x16x32_bf16(a[(S)*4 + k2], bfr, hacc[ct], 0, 0, 0); \
    } \
  } \
  __builtin_amdgcn_s_setprio(0); \
}while(0)

#define G2_PHASE(NB, BUF) do{ \
  __builtin_amdgcn_s_setprio(1); \
  _Pragma("unroll") \
  for (int nt = 0; nt < 8; ++nt){ \
    const int col = (nt << 4) + lrow; \
    const int swc = (col & 7) << 4; \
    _Pragma("unroll") \
    for (int k2 = 0; k2 < 2; ++k2){ \
      const int byt = (col << 7) + (((k2 << 6) + (kgrp << 4)) ^ swc); \
      bf16x8 bfr = *(const bf16x8*)((const char*)(BUF) + byt); \
      acc[(NB)*8 + nt] = __builtin_amdgcn_mfma_f32_16x16x32_bf16(a2[k2], bfr, acc[(NB)*8 + nt], 0, 0, 0); \
    } \
  } \
  __builtin_amdgcn_s_setprio(0); \
}while(0)

__global__ __launch_bounds__(512, 2)
void expert_kernel(const float* __restrict__ x,
                   const unsigned short* __restrict__ we1T,  // [E][1024][512] bf16
                   const unsigned short* __restrict__ we2T,  // [E][512][1024] bf16
                   const float* __restrict__ be1, const float* __restrict__ be2,
                   const int* __restrict__ counts, const int* __restrict__ pair_tok,
                   const float* __restrict__ pair_w,
                   float* __restrict__ out){
  const int e = blockIdx.x >> 9;         // sequential experts
  const int blk = blockIdx.x & 511;
  const int cnt = counts[e];
  const int base = blk << 7;             // 128 tokens per block
  if (base >= cnt) return;
  const int tid = threadIdx.x;
  const int wv = tid >> 6;               // 0..7
  const int lane = tid & 63;
  const int lrow = lane & 15;
  const int kgrp = lane >> 4;

  __shared__ unsigned short w1s0[64 * 128];   // [hcol][k] 16KB (K=128 piece)
  __shared__ unsigned short w1s1[64 * 128];
  __shared__ unsigned short w2s0[128 * 64];   // [dcol][k] 16KB (128-dcol piece)
  __shared__ unsigned short w2s1[128 * 64];
  __shared__ unsigned short hs[128 * 64];     // [row][k]   16KB

  // A fragments: x rows (bf16), full K=512
  bf16x8 a[16];
  {
    int r = base + (wv << 4) + lrow;
    int tok = (r < cnt) ? pair_tok[(e << 16) + r] : 0;
    const float* xr = x + (size_t)tok * 512 + (kgrp << 3);
    #pragma unroll
    for (int kc = 0; kc < 16; ++kc){
      const float4 f0 = *(const float4*)(xr + (kc << 5));
      const float4 f1 = *(const float4*)(xr + (kc << 5) + 4);
      a[kc] = cvt8(f0, f1);
    }
  }
  f32x4 acc[32];
  #pragma unroll
  for (int i = 0; i < 32; ++i) acc[i] = (f32x4)0.f;

  const unsigned short* w1g = we1T + ((size_t)e << 19);
  const unsigned short* w2g = we2T + ((size_t)e << 19);

  // async staging: 16KB piece = 8 waves x 2 gload16; LDS dest linear,
  // global src pre-swizzled (XOR (row&7)<<4 within the row).
  auto stage_w1 = [&](int hcv, int s, unsigned short* buf){
    #pragma unroll
    for (int i = 0; i < 2; ++i){
      int b = (((wv << 1) + i) << 10) + (lane << 4);
      int row = b >> 8;                 // [64][128] bf16, 256B rows
      int inner = b & 255;
      int srcb = ((hcv + row) << 10) + (s << 8) + (inner ^ ((row & 7) << 4));
      gload16((const char*)w1g + srcb, (char*)buf + (((wv << 1) + i) << 10));
    }
  };
  auto stage_w2 = [&](int hcv, int nb, unsigned short* buf){
    #pragma unroll
    for (int i = 0; i < 2; ++i){
      int b = (((wv << 1) + i) << 10) + (lane << 4);
      int row = b >> 7;                 // [128][64] bf16, 128B rows
      int inner = b & 127;
      int srcb = (((nb << 7) + row) << 11) + (hcv << 1) + (inner ^ ((row & 7) << 4));
      gload16((const char*)w2g + srcb, (char*)buf + (((wv << 1) + i) << 10));
    }
  };

  stage_w1(0, 0, w1s0);
  __syncthreads();

  for (int hc = 0; hc < 1024; hc += 64){
    f32x4 hacc[4];
    #pragma unroll
    for (int i = 0; i < 4; ++i) hacc[i] = (f32x4)0.f;

    stage_w1(hc, 1, w1s1);  G1_PHASE(0, w1s0);  __syncthreads();
    stage_w1(hc, 2, w1s0);  G1_PHASE(1, w1s1);  __syncthreads();
    stage_w1(hc, 3, w1s1);  G1_PHASE(2, w1s0);  __syncthreads();
    stage_w2(hc, 0, w2s0);  G1_PHASE(3, w1s1);
    { // bias + exact gelu + store h (bf16, swizzled)
      char* const hsb = (char*)hs;
      #pragma unroll
      for (int ct = 0; ct < 4; ++ct){
        int colL = (ct << 4) + lrow;
        float bias = be1[(e << 10) + hc + colL];
        #pragma unroll
        for (int rr = 0; rr < 4; ++rr){
          int rowL = (wv << 4) + (kgrp << 2) + rr;
          float v = hacc[ct][rr] + bias;
          float g = 0.5f * v * (1.f + erff(v * 0.70710678118654752f));
          int byt = (rowL << 7) + (colL << 1);
          *(unsigned short*)(hsb + (byt ^ ((rowL & 7) << 4))) = f2bf(g);
        }
      }
    }
    __syncthreads();
    bf16x8 a2[2];
    {
      const char* const hsb = (const char*)hs;
      int rowL = (wv << 4) + lrow;
      int swr = (rowL & 7) << 4;
      #pragma unroll
      for (int k2 = 0; k2 < 2; ++k2){
        int byt = (rowL << 7) + (((k2 << 6) + (kgrp << 4)) ^ swr);
        a2[k2] = *(const bf16x8*)(hsb + byt);
      }
    }
    stage_w2(hc, 1, w2s1);                G2_PHASE(0, w2s0);  __syncthreads();
    stage_w2(hc, 2, w2s0);                G2_PHASE(1, w2s1);  __syncthreads();
    stage_w2(hc, 3, w2s1);                G2_PHASE(2, w2s0);  __syncthreads();
    stage_w1((hc + 64) & 1023, 0, w1s0);  G2_PHASE(3, w2s1);  __syncthreads();
  }

  // epilogue: weighted atomic accumulate
  #pragma unroll
  for (int rr = 0; rr < 4; ++rr){
    int rowL = (wv << 4) + (kgrp << 2) + rr;
    int rg = base + rowL;
    if (rg < cnt){
      int tok = pair_tok[(e << 16) + rg];
      float wp = pair_w[(e << 16) + rg];
      float* orow = out + (size_t)tok * 512;
      #pragma unroll
      for (int tl = 0; tl < 32; ++tl){
        int col = (tl << 4) + lrow;
        atomicAdd(orow + col, wp * (acc[tl][rr] + be2[(e << 9) + col]));
      }
    }
  }
}

// ---------------------------------------------------------------------------
extern "C" void kernel_launch(void* const* d_in, const int* in_sizes, int n_in,
                              void* d_out, int out_size, void* d_ws, size_t ws_size,
                              hipStream_t stream){
  const float* x   = (const float*)d_in[0];
  const float* gw1 = (const float*)d_in[1];
  const float* gb1 = (const float*)d_in[2];
  const float* gw2 = (const float*)d_in[3];
  const float* gb2 = (const float*)d_in[4];
  const float* we1 = (const float*)d_in[5];
  const float* be1 = (const float*)d_in[6];
  const float* we2 = (const float*)d_in[7];
  const float* be2 = (const float*)d_in[8];
  float* out = (float*)d_out;

  char* ws = (char*)d_ws;
  unsigned short* we1T = (unsigned short*)(ws);                    // 8 MiB
  unsigned short* we2T = (unsigned short*)(ws + 8388608);          // 8 MiB
  int*   counts   = (int*)  (ws + 16777216);                       // 32 B
  int*   pair_tok = (int*)  (ws + 16777472);                       // 2 MiB
  float* pair_w   = (float*)(ws + 16777472 + 2097152);             // 2 MiB

  hipMemsetAsync(d_out, 0, (size_t)out_size * sizeof(float), stream);
  hipMemsetAsync(counts, 0, 32, stream);

  hipLaunchKernelGGL(transpose_cvt_kernel, dim3(1024), dim3(256), 0, stream,
                     we1, we1T, 512, 1024);
  hipLaunchKernelGGL(transpose_cvt_kernel, dim3(1024), dim3(256), 0, stream,
                     we2, we2T, 1024, 512);
  hipLaunchKernelGGL(gate_kernel, dim3(512), dim3(512), 0, stream,
                     x, gw1, gb1, gw2, gb2, counts, pair_tok, pair_w);
  hipLaunchKernelGGL(expert_kernel, dim3(4096), dim3(512), 0, stream,
                     x, we1T, we2T, be1, be2, counts, pair_tok, pair_w, out);
}